// Round 5
// baseline (658.606 us; speedup 1.0000x reference)
//
#include <hip/hip_runtime.h>
#include <hip/hip_bf16.h>

#define Nn 8192
#define Ee 8192
#define Hh 256
#define MASK_W 128   // 8192 bits / 64

typedef unsigned long long u64;

// ---------------------------------------------------------------------------
// Kernel 1: precompute. u = Wc@v, w2 = Wf@v, g = u + Wx@u, scalar consts.
// consts[0]=bx.u ; consts[1]=beta*(bc.v)+bf.v+bs ; consts[2]=sign ; consts[3]=beta
// Wave-per-output-row mapping: coalesced 256B/instr weight reads.
// ---------------------------------------------------------------------------
__global__ void __launch_bounds__(256)
pre_kernel(const float* __restrict__ Wx, const float* __restrict__ bx,
           const float* __restrict__ Wc, const float* __restrict__ bc,
           const float* __restrict__ Wf, const float* __restrict__ bf_,
           const float* __restrict__ v_, const float* __restrict__ bs,
           const float* __restrict__ beta, const int* __restrict__ boolen,
           float* __restrict__ u, float* __restrict__ w2,
           float* __restrict__ g, float* __restrict__ consts) {
    __shared__ float sv[Hh];
    __shared__ float su[Hh];
    __shared__ float red[Hh];
    const int tid = threadIdx.x;
    const int wave = tid >> 6;
    const int lane = tid & 63;
    sv[tid] = v_[tid];
    __syncthreads();

    // u[k] = Wc[k,:].v ; w2[k] = Wf[k,:].v  — wave handles k = 4p+wave
    for (int p = 0; p < 64; ++p) {
        const int k = p * 4 + wave;
        float a = 0.f, b = 0.f;
#pragma unroll
        for (int i = 0; i < 4; ++i) {
            const int j = lane + 64 * i;
            a = fmaf(Wc[k * Hh + j], sv[j], a);
            b = fmaf(Wf[k * Hh + j], sv[j], b);
        }
        for (int off = 32; off > 0; off >>= 1) { a += __shfl_down(a, off); b += __shfl_down(b, off); }
        if (lane == 0) { su[k] = a; u[k] = a; w2[k] = b; }
    }
    __syncthreads();
    // g[k] = u[k] + Wx[k,:].u
    for (int p = 0; p < 64; ++p) {
        const int k = p * 4 + wave;
        float a = 0.f;
#pragma unroll
        for (int i = 0; i < 4; ++i) {
            const int j = lane + 64 * i;
            a = fmaf(Wx[k * Hh + j], su[j], a);
        }
        for (int off = 32; off > 0; off >>= 1) a += __shfl_down(a, off);
        if (lane == 0) g[k] = su[k] + a;
    }

    // scalar consts via LDS ladder (coalesced, tiny)
    red[tid] = bc[tid] * sv[tid];
    __syncthreads();
    for (int s = 128; s > 0; s >>= 1) { if (tid < s) red[tid] += red[tid + s]; __syncthreads(); }
    const float bcv = red[0];
    __syncthreads();
    red[tid] = bf_[tid] * sv[tid];
    __syncthreads();
    for (int s = 128; s > 0; s >>= 1) { if (tid < s) red[tid] += red[tid + s]; __syncthreads(); }
    const float bfv = red[0];
    __syncthreads();
    red[tid] = bx[tid] * su[tid];
    __syncthreads();
    for (int s = 128; s > 0; s >>= 1) { if (tid < s) red[tid] += red[tid + s]; __syncthreads(); }
    if (tid == 0) {
        const float be = beta[0];
        consts[0] = red[0];
        consts[1] = be * bcv + bfv + bs[0];
        consts[2] = (boolen[0] != 0) ? 1.f : -1.f;
        consts[3] = be;
    }
}

// ---------------------------------------------------------------------------
// Kernel 2: ballot bit-pack. One wave per adj row; lane l reads row[w*64+l]
// (fully coalesced 256B/instr); __ballot(v!=0) IS the u64 mask word.
// ---------------------------------------------------------------------------
__global__ void __launch_bounds__(256)
pack_kernel(const float* __restrict__ adj, u64* __restrict__ mask) {
    const int row = (blockIdx.x << 2) | (threadIdx.x >> 6);  // global wave id
    const int lane = threadIdx.x & 63;
    const float* r = adj + (size_t)row * Nn;
    u64* mrow = mask + (size_t)row * MASK_W;
#pragma unroll 4
    for (int w = 0; w < MASK_W; ++w) {
        const float v = r[w * 64 + lane];
        const u64 bal = __ballot(v != 0.f);
        if (lane == 0) mrow[w] = bal;
    }
}

// ---------------------------------------------------------------------------
// Kernel 3: P = x@Wi + bi, Q = x@Wj + bj (fp32), plus t[n] = x[n].g + c0.
// 16 rows/block; x staged in LDS; weights read per-k (lane-coalesced, L2-hot).
// ---------------------------------------------------------------------------
#define RQ 16
__global__ void __launch_bounds__(256)
pq_kernel(const float* __restrict__ x,
          const float* __restrict__ Wi, const float* __restrict__ Wj,
          const float* __restrict__ bi, const float* __restrict__ bj,
          const float* __restrict__ g, const float* __restrict__ consts,
          float* __restrict__ P, float* __restrict__ Q, float* __restrict__ t) {
    __shared__ float xs[RQ][Hh];                 // 16 KB
    const int tid = threadIdx.x;
    const int base = blockIdx.x * RQ;

    {
        const float4* xv = reinterpret_cast<const float4*>(x + (size_t)base * Hh);
        float4* xd = reinterpret_cast<float4*>(&xs[0][0]);
#pragma unroll
        for (int i = tid; i < 1024; i += 256) xd[i] = xv[i];
    }
    __syncthreads();

    // t for this block's rows: wave w handles rows 4w..4w+3
    {
        const int wave = tid >> 6;
        const int lane = tid & 63;
        const float c0 = consts[0];
#pragma unroll
        for (int r0 = 0; r0 < 4; ++r0) {
            const int r = wave * 4 + r0;
            float s = 0.f;
#pragma unroll
            for (int i = 0; i < 4; ++i) {
                const int c = lane * 4 + i;
                s = fmaf(xs[r][c], g[c], s);
            }
            for (int off = 32; off > 0; off >>= 1) s += __shfl_down(s, off);
            if (lane == 0) t[base + r] = s + c0;
        }
    }

    float accP[RQ], accQ[RQ];
    const float fbi = bi[tid], fbj = bj[tid];
#pragma unroll
    for (int r = 0; r < RQ; ++r) { accP[r] = fbi; accQ[r] = fbj; }

#pragma unroll 4
    for (int k = 0; k < Hh; ++k) {
        const float wiv = Wi[k * Hh + tid];
        const float wjv = Wj[k * Hh + tid];
#pragma unroll
        for (int r = 0; r < RQ; ++r) {
            accP[r] = fmaf(xs[r][k], wiv, accP[r]);
            accQ[r] = fmaf(xs[r][k], wjv, accQ[r]);
        }
    }
#pragma unroll
    for (int r = 0; r < RQ; ++r) {
        P[(size_t)(base + r) * Hh + tid] = accP[r];
        Q[(size_t)(base + r) * Hh + tid] = accQ[r];
    }
}

// ---------------------------------------------------------------------------
// Kernel 4: per-edge block.
// accA = sum of t[n] over common-neighbor bits; accB = relu(P[src]+Q[dst]).w2
// out = softplus(-sign*(beta*accA + accB + c1))
// ---------------------------------------------------------------------------
__global__ void __launch_bounds__(256)
edge_kernel(const u64* __restrict__ mask, const int* __restrict__ tei,
            const float* __restrict__ P, const float* __restrict__ Q,
            const float* __restrict__ w2, const float* __restrict__ t,
            const float* __restrict__ consts, float* __restrict__ out) {
    const int e = blockIdx.x;
    const int tid = threadIdx.x;
    const int src = tei[e];
    const int dst = tei[Ee + e];

    float accA = 0.f;
    if (tid < MASK_W) {
        u64 m = mask[(size_t)src * MASK_W + tid] & mask[(size_t)dst * MASK_W + tid];
        while (m) {
            const int b = __builtin_ctzll(m);
            accA += t[tid * 64 + b];
            m &= m - 1;
        }
    }
    const float r = P[(size_t)src * Hh + tid] + Q[(size_t)dst * Hh + tid];
    float accB = fmaxf(r, 0.f) * w2[tid];

    for (int off = 32; off > 0; off >>= 1) {
        accA += __shfl_down(accA, off);
        accB += __shfl_down(accB, off);
    }
    __shared__ float wA[4], wB[4];
    const int wave = tid >> 6;
    if ((tid & 63) == 0) { wA[wave] = accA; wB[wave] = accB; }
    __syncthreads();
    if (tid == 0) {
        const float sA = wA[0] + wA[1] + wA[2] + wA[3];
        const float sB = wB[0] + wB[1] + wB[2] + wB[3];
        const float be = consts[3];
        const float sgn = consts[2];
        const float s = be * sA + sB + consts[1];
        const float m = -sgn * s;
        const float res = fmaxf(m, 0.f) + log1pf(expf(-fabsf(m)));
        out[e] = res;
    }
}

extern "C" void kernel_launch(void* const* d_in, const int* in_sizes, int n_in,
                              void* d_out, int out_size, void* d_ws, size_t ws_size,
                              hipStream_t stream) {
    const float* x     = (const float*)d_in[0];
    const float* adj   = (const float*)d_in[1];
    const int*   tei   = (const int*)d_in[2];
    const float* Wx    = (const float*)d_in[3];
    const float* bx    = (const float*)d_in[4];
    const float* Wc    = (const float*)d_in[5];
    const float* bc    = (const float*)d_in[6];
    const float* Wi    = (const float*)d_in[7];
    const float* bi    = (const float*)d_in[8];
    const float* Wj    = (const float*)d_in[9];
    const float* bj    = (const float*)d_in[10];
    const float* Wf    = (const float*)d_in[11];
    const float* bf_   = (const float*)d_in[12];
    const float* v_    = (const float*)d_in[13];
    const float* bs    = (const float*)d_in[14];
    const float* beta  = (const float*)d_in[15];
    const int*   booln = (const int*)d_in[16];
    float* out = (float*)d_out;

    // workspace layout (fp32 elements)
    float* u      = (float*)d_ws;                // 256
    float* w2     = u + 256;                     // 256
    float* g      = w2 + 256;                    // 256
    float* consts = g + 256;                     // 8 (padded)
    float* t      = consts + 8;                  // 8192
    float* P      = t + 8192;                    // 8 MB
    float* Q      = P + (size_t)Nn * Hh;         // 8 MB
    u64*   mask   = (u64*)(Q + (size_t)Nn * Hh); // 8 MB
    // total ~25 MB << ws_size

    pre_kernel<<<1, 256, 0, stream>>>(Wx, bx, Wc, bc, Wf, bf_, v_, bs, beta, booln,
                                      u, w2, g, consts);
    pack_kernel<<<Nn / 4, 256, 0, stream>>>(adj, mask);
    pq_kernel<<<Nn / RQ, 256, 0, stream>>>(x, Wi, Wj, bi, bj, g, consts, P, Q, t);
    edge_kernel<<<Ee, 256, 0, stream>>>(mask, tei, P, Q, w2, t, consts, out);
}

// Round 7
// 568.581 us; speedup vs baseline: 1.1583x; 1.1583x over previous
//
#include <hip/hip_runtime.h>
#include <hip/hip_bf16.h>

#define Nn 8192
#define Ee 8192
#define Hh 256
#define MASK_W 128   // 8192 bits / 64

typedef unsigned long long u64;

// ---------------------------------------------------------------------------
// Kernel 1: tiny precompute. u = Wc@v, w2 = Wf@v, g = u + Wx@u, scalar consts.
// consts[0]=bx.u ; consts[1]=beta*(bc.v)+bf.v+bs ; consts[2]=sign ; consts[3]=beta
// ---------------------------------------------------------------------------
__global__ void pre_kernel(const float* __restrict__ Wx, const float* __restrict__ bx,
                           const float* __restrict__ Wc, const float* __restrict__ bc,
                           const float* __restrict__ Wf, const float* __restrict__ bf_,
                           const float* __restrict__ v_, const float* __restrict__ bs,
                           const float* __restrict__ beta, const int* __restrict__ boolen,
                           float* __restrict__ u, float* __restrict__ w2,
                           float* __restrict__ g, float* __restrict__ consts) {
    __shared__ float sv[Hh];
    __shared__ float su[Hh];
    __shared__ float red[Hh];
    const int k = threadIdx.x;
    sv[k] = v_[k];
    __syncthreads();
    float uk = 0.f, w2k = 0.f;
    for (int j = 0; j < Hh; ++j) {
        uk  = fmaf(Wc[k * Hh + j], sv[j], uk);
        w2k = fmaf(Wf[k * Hh + j], sv[j], w2k);
    }
    su[k] = uk;
    __syncthreads();
    float gk = uk;
    for (int j = 0; j < Hh; ++j) gk = fmaf(Wx[k * Hh + j], su[j], gk);
    u[k] = uk; w2[k] = w2k; g[k] = gk;

    red[k] = bc[k] * sv[k];
    __syncthreads();
    for (int s = 128; s > 0; s >>= 1) { if (k < s) red[k] += red[k + s]; __syncthreads(); }
    const float bcv = red[0];
    __syncthreads();
    red[k] = bf_[k] * sv[k];
    __syncthreads();
    for (int s = 128; s > 0; s >>= 1) { if (k < s) red[k] += red[k + s]; __syncthreads(); }
    const float bfv = red[0];
    __syncthreads();
    red[k] = bx[k] * su[k];
    __syncthreads();
    for (int s = 128; s > 0; s >>= 1) { if (k < s) red[k] += red[k + s]; __syncthreads(); }
    if (k == 0) {
        const float be = beta[0];
        consts[0] = red[0];
        consts[1] = be * bcv + bfv + bs[0];
        consts[2] = (boolen[0] != 0) ? 1.f : -1.f;
        consts[3] = be;
    }
}

// ---------------------------------------------------------------------------
// Kernel 2: bit-pack adj (f32 0/1) into u64 masks. One thread -> one u64.
// mask[row][col] bit b  <=>  adj[row][col*64+b] != 0
// ---------------------------------------------------------------------------
__global__ void pack_kernel(const float* __restrict__ adj, u64* __restrict__ mask) {
    const int gid = blockIdx.x * blockDim.x + threadIdx.x;   // 0 .. 8192*128-1
    const int row = gid >> 7;
    const int col = gid & 127;
    const float4* p = reinterpret_cast<const float4*>(adj + (size_t)row * Nn + col * 64);
    u64 m = 0;
#pragma unroll
    for (int q = 0; q < 16; ++q) {
        const float4 v = p[q];
        if (v.x != 0.f) m |= 1ull << (q * 4 + 0);
        if (v.y != 0.f) m |= 1ull << (q * 4 + 1);
        if (v.z != 0.f) m |= 1ull << (q * 4 + 2);
        if (v.w != 0.f) m |= 1ull << (q * 4 + 3);
    }
    mask[gid] = m;
}

// ---------------------------------------------------------------------------
// Kernel 3: P = x@Wi + bi, Q = x@Wj + bj (fp32), plus t[n] = x[n].g + c0.
// 16 rows/block; x staged in LDS; weights read per-k (lane-coalesced, L2-hot).
// ---------------------------------------------------------------------------
#define RQ 16
__global__ void __launch_bounds__(256)
pq_kernel(const float* __restrict__ x,
          const float* __restrict__ Wi, const float* __restrict__ Wj,
          const float* __restrict__ bi, const float* __restrict__ bj,
          const float* __restrict__ g, const float* __restrict__ consts,
          float* __restrict__ P, float* __restrict__ Q, float* __restrict__ t) {
    __shared__ float xs[RQ][Hh];                 // 16 KB
    const int tid = threadIdx.x;
    const int base = blockIdx.x * RQ;

    // stage x rows: RQ*Hh = 4096 floats = 1024 float4
    {
        const float4* xv = reinterpret_cast<const float4*>(x + (size_t)base * Hh);
        float4* xd = reinterpret_cast<float4*>(&xs[0][0]);
#pragma unroll
        for (int i = tid; i < 1024; i += 256) xd[i] = xv[i];
    }
    __syncthreads();

    // t for this block's rows: wave w handles rows 4w..4w+3
    {
        const int wave = tid >> 6;
        const int lane = tid & 63;
        const float c0 = consts[0];
#pragma unroll
        for (int r0 = 0; r0 < 4; ++r0) {
            const int r = wave * 4 + r0;
            float s = 0.f;
#pragma unroll
            for (int i = 0; i < 4; ++i) {
                const int c = lane * 4 + i;
                s = fmaf(xs[r][c], g[c], s);
            }
            for (int off = 32; off > 0; off >>= 1) s += __shfl_down(s, off);
            if (lane == 0) t[base + r] = s + c0;
        }
    }

    float accP[RQ], accQ[RQ];
    const float fbi = bi[tid], fbj = bj[tid];
#pragma unroll
    for (int r = 0; r < RQ; ++r) { accP[r] = fbi; accQ[r] = fbj; }

#pragma unroll 4
    for (int k = 0; k < Hh; ++k) {
        const float wiv = Wi[k * Hh + tid];
        const float wjv = Wj[k * Hh + tid];
#pragma unroll
        for (int r = 0; r < RQ; ++r) {
            accP[r] = fmaf(xs[r][k], wiv, accP[r]);
            accQ[r] = fmaf(xs[r][k], wjv, accQ[r]);
        }
    }
#pragma unroll
    for (int r = 0; r < RQ; ++r) {
        P[(size_t)(base + r) * Hh + tid] = accP[r];
        Q[(size_t)(base + r) * Hh + tid] = accQ[r];
    }
}

// ---------------------------------------------------------------------------
// Kernel 4: per-edge block.
// accA = sum over common-neighbor bits of t[n]; accB = relu(P[src]+Q[dst]).w2
// out = softplus(-sign*(beta*accA + accB + c1))
// ---------------------------------------------------------------------------
__global__ void edge_kernel(const u64* __restrict__ mask, const int* __restrict__ tei,
                            const float* __restrict__ P, const float* __restrict__ Q,
                            const float* __restrict__ w2, const float* __restrict__ t,
                            const float* __restrict__ consts, float* __restrict__ out) {
    const int e = blockIdx.x;
    const int tid = threadIdx.x;
    const int src = tei[e];
    const int dst = tei[Ee + e];

    __shared__ u64 ms[MASK_W];
    __shared__ u64 md[MASK_W];
    if (tid < MASK_W) ms[tid] = mask[(size_t)src * MASK_W + tid];
    else              md[tid - MASK_W] = mask[(size_t)dst * MASK_W + (tid - MASK_W)];
    __syncthreads();

    float accA = 0.f;
    if (tid < MASK_W) {
        u64 m = ms[tid] & md[tid];
        while (m) {
            const int b = __builtin_ctzll(m);
            accA += t[tid * 64 + b];
            m &= m - 1;
        }
    }
    const float r = P[(size_t)src * Hh + tid] + Q[(size_t)dst * Hh + tid];
    float accB = (r > 0.f) ? r * w2[tid] : 0.f;

    for (int off = 32; off > 0; off >>= 1) {
        accA += __shfl_down(accA, off);
        accB += __shfl_down(accB, off);
    }
    __shared__ float wA[4], wB[4];
    const int wave = tid >> 6;
    if ((tid & 63) == 0) { wA[wave] = accA; wB[wave] = accB; }
    __syncthreads();
    if (tid == 0) {
        const float sA = wA[0] + wA[1] + wA[2] + wA[3];
        const float sB = wB[0] + wB[1] + wB[2] + wB[3];
        const float be = consts[3];
        const float sgn = consts[2];
        const float s = be * sA + sB + consts[1];
        const float m = -sgn * s;
        const float res = fmaxf(m, 0.f) + log1pf(expf(-fabsf(m)));
        out[e] = res;
    }
}

extern "C" void kernel_launch(void* const* d_in, const int* in_sizes, int n_in,
                              void* d_out, int out_size, void* d_ws, size_t ws_size,
                              hipStream_t stream) {
    const float* x     = (const float*)d_in[0];
    const float* adj   = (const float*)d_in[1];
    const int*   tei   = (const int*)d_in[2];
    const float* Wx    = (const float*)d_in[3];
    const float* bx    = (const float*)d_in[4];
    const float* Wc    = (const float*)d_in[5];
    const float* bc    = (const float*)d_in[6];
    const float* Wi    = (const float*)d_in[7];
    const float* bi    = (const float*)d_in[8];
    const float* Wj    = (const float*)d_in[9];
    const float* bj    = (const float*)d_in[10];
    const float* Wf    = (const float*)d_in[11];
    const float* bf_   = (const float*)d_in[12];
    const float* v_    = (const float*)d_in[13];
    const float* bs    = (const float*)d_in[14];
    const float* beta  = (const float*)d_in[15];
    const int*   booln = (const int*)d_in[16];
    float* out = (float*)d_out;

    // workspace layout (fp32 elements)
    float* u      = (float*)d_ws;                // 256
    float* w2     = u + 256;                     // 256
    float* g      = w2 + 256;                    // 256
    float* consts = g + 256;                     // 8 (padded)
    float* t      = consts + 8;                  // 8192
    float* P      = t + 8192;                    // 8192*256 = 8 MB
    float* Q      = P + (size_t)Nn * Hh;         // 8 MB
    u64*   mask   = (u64*)(Q + (size_t)Nn * Hh); // 8192*128 u64 = 8 MB
    // total ~25 MB << ws_size

    pack_kernel<<<(Nn * MASK_W) / 256, 256, 0, stream>>>(adj, mask);
    pre_kernel<<<1, 256, 0, stream>>>(Wx, bx, Wc, bc, Wf, bf_, v_, bs, beta, booln,
                                      u, w2, g, consts);
    pq_kernel<<<Nn / RQ, 256, 0, stream>>>(x, Wi, Wj, bi, bj, g, consts, P, Q, t);
    edge_kernel<<<Ee, 256, 0, stream>>>(mask, tei, P, Q, w2, t, consts, out);
}

// Round 8
// 536.470 us; speedup vs baseline: 1.2277x; 1.0599x over previous
//
#include <hip/hip_runtime.h>
#include <hip/hip_bf16.h>

#define Nn 8192
#define Ee 8192
#define Hh 256
#define MASK_W 128   // 8192 bits / 64

typedef unsigned long long u64;

// ---------------------------------------------------------------------------
// Kernel 1a: preA — parallel precompute stage 1.
// blocks 0..63 : u[k] = Wc[k,:].v ; w2[k] = Wf[k,:].v   (k = blk*4 + wave)
// block  64    : consts[1] = beta*(bc.v) + bf.v + bs ; consts[2]=sign ; consts[3]=beta
// ---------------------------------------------------------------------------
__global__ void __launch_bounds__(256)
preA_kernel(const float* __restrict__ Wc, const float* __restrict__ Wf,
            const float* __restrict__ v_, const float* __restrict__ bc,
            const float* __restrict__ bf_, const float* __restrict__ bs,
            const float* __restrict__ beta, const int* __restrict__ boolen,
            float* __restrict__ u, float* __restrict__ w2,
            float* __restrict__ consts) {
    const int tid = threadIdx.x;
    if (blockIdx.x < 64) {
        const int wave = tid >> 6;
        const int lane = tid & 63;
        const int k = blockIdx.x * 4 + wave;
        float a = 0.f, b = 0.f;
#pragma unroll
        for (int i = 0; i < 4; ++i) {
            const int j = lane + 64 * i;
            const float vv = v_[j];
            a = fmaf(Wc[k * Hh + j], vv, a);
            b = fmaf(Wf[k * Hh + j], vv, b);
        }
        for (int off = 32; off > 0; off >>= 1) {
            a += __shfl_down(a, off);
            b += __shfl_down(b, off);
        }
        if (lane == 0) { u[k] = a; w2[k] = b; }
        return;
    }
    // block 64: scalar consts that don't need u
    __shared__ float red[Hh];
    __shared__ float red2[Hh];
    const float vv = v_[tid];
    red[tid]  = bc[tid]  * vv;
    red2[tid] = bf_[tid] * vv;
    __syncthreads();
    for (int s = 128; s > 0; s >>= 1) {
        if (tid < s) { red[tid] += red[tid + s]; red2[tid] += red2[tid + s]; }
        __syncthreads();
    }
    if (tid == 0) {
        const float be = beta[0];
        consts[1] = be * red[0] + red2[0] + bs[0];
        consts[2] = (boolen[0] != 0) ? 1.f : -1.f;
        consts[3] = be;
    }
}

// ---------------------------------------------------------------------------
// Kernel 1b: preB — parallel precompute stage 2 (consumes u from preA).
// blocks 0..63 : g[k] = u[k] + Wx[k,:].u   (k = blk*4 + wave)
// block  64    : consts[0] = bx.u
// ---------------------------------------------------------------------------
__global__ void __launch_bounds__(256)
preB_kernel(const float* __restrict__ Wx, const float* __restrict__ bx,
            const float* __restrict__ u, float* __restrict__ g,
            float* __restrict__ consts) {
    const int tid = threadIdx.x;
    if (blockIdx.x < 64) {
        const int wave = tid >> 6;
        const int lane = tid & 63;
        const int k = blockIdx.x * 4 + wave;
        float a = 0.f;
#pragma unroll
        for (int i = 0; i < 4; ++i) {
            const int j = lane + 64 * i;
            a = fmaf(Wx[k * Hh + j], u[j], a);
        }
        for (int off = 32; off > 0; off >>= 1) a += __shfl_down(a, off);
        if (lane == 0) g[k] = u[k] + a;
        return;
    }
    // block 64: consts[0] = bx.u
    __shared__ float red[Hh];
    red[tid] = bx[tid] * u[tid];
    __syncthreads();
    for (int s = 128; s > 0; s >>= 1) { if (tid < s) red[tid] += red[tid + s]; __syncthreads(); }
    if (tid == 0) consts[0] = red[0];
}

// ---------------------------------------------------------------------------
// Kernel 2: bit-pack adj (f32 0/1) into u64 masks. One thread -> one u64.
// (identical to R4/R7 measured-good body)
// ---------------------------------------------------------------------------
__global__ void pack_kernel(const float* __restrict__ adj, u64* __restrict__ mask) {
    const int gid = blockIdx.x * blockDim.x + threadIdx.x;   // 0 .. 8192*128-1
    const int row = gid >> 7;
    const int col = gid & 127;
    const float4* p = reinterpret_cast<const float4*>(adj + (size_t)row * Nn + col * 64);
    u64 m = 0;
#pragma unroll
    for (int q = 0; q < 16; ++q) {
        const float4 v = p[q];
        if (v.x != 0.f) m |= 1ull << (q * 4 + 0);
        if (v.y != 0.f) m |= 1ull << (q * 4 + 1);
        if (v.z != 0.f) m |= 1ull << (q * 4 + 2);
        if (v.w != 0.f) m |= 1ull << (q * 4 + 3);
    }
    mask[gid] = m;
}

// ---------------------------------------------------------------------------
// Kernel 3: P = x@Wi + bi, Q = x@Wj + bj (fp32), plus t[n] = x[n].g + c0.
// (identical to R4/R7 measured-good kernel)
// ---------------------------------------------------------------------------
#define RQ 16
__global__ void __launch_bounds__(256)
pq_kernel(const float* __restrict__ x,
          const float* __restrict__ Wi, const float* __restrict__ Wj,
          const float* __restrict__ bi, const float* __restrict__ bj,
          const float* __restrict__ g, const float* __restrict__ consts,
          float* __restrict__ P, float* __restrict__ Q, float* __restrict__ t) {
    __shared__ float xs[RQ][Hh];                 // 16 KB
    const int tid = threadIdx.x;
    const int base = blockIdx.x * RQ;

    {
        const float4* xv = reinterpret_cast<const float4*>(x + (size_t)base * Hh);
        float4* xd = reinterpret_cast<float4*>(&xs[0][0]);
#pragma unroll
        for (int i = tid; i < 1024; i += 256) xd[i] = xv[i];
    }
    __syncthreads();

    {
        const int wave = tid >> 6;
        const int lane = tid & 63;
        const float c0 = consts[0];
#pragma unroll
        for (int r0 = 0; r0 < 4; ++r0) {
            const int r = wave * 4 + r0;
            float s = 0.f;
#pragma unroll
            for (int i = 0; i < 4; ++i) {
                const int c = lane * 4 + i;
                s = fmaf(xs[r][c], g[c], s);
            }
            for (int off = 32; off > 0; off >>= 1) s += __shfl_down(s, off);
            if (lane == 0) t[base + r] = s + c0;
        }
    }

    float accP[RQ], accQ[RQ];
    const float fbi = bi[tid], fbj = bj[tid];
#pragma unroll
    for (int r = 0; r < RQ; ++r) { accP[r] = fbi; accQ[r] = fbj; }

#pragma unroll 4
    for (int k = 0; k < Hh; ++k) {
        const float wiv = Wi[k * Hh + tid];
        const float wjv = Wj[k * Hh + tid];
#pragma unroll
        for (int r = 0; r < RQ; ++r) {
            accP[r] = fmaf(xs[r][k], wiv, accP[r]);
            accQ[r] = fmaf(xs[r][k], wjv, accQ[r]);
        }
    }
#pragma unroll
    for (int r = 0; r < RQ; ++r) {
        P[(size_t)(base + r) * Hh + tid] = accP[r];
        Q[(size_t)(base + r) * Hh + tid] = accQ[r];
    }
}

// ---------------------------------------------------------------------------
// Kernel 4: per-edge block (identical to R4/R7 measured-good kernel).
// ---------------------------------------------------------------------------
__global__ void edge_kernel(const u64* __restrict__ mask, const int* __restrict__ tei,
                            const float* __restrict__ P, const float* __restrict__ Q,
                            const float* __restrict__ w2, const float* __restrict__ t,
                            const float* __restrict__ consts, float* __restrict__ out) {
    const int e = blockIdx.x;
    const int tid = threadIdx.x;
    const int src = tei[e];
    const int dst = tei[Ee + e];

    __shared__ u64 ms[MASK_W];
    __shared__ u64 md[MASK_W];
    if (tid < MASK_W) ms[tid] = mask[(size_t)src * MASK_W + tid];
    else              md[tid - MASK_W] = mask[(size_t)dst * MASK_W + (tid - MASK_W)];
    __syncthreads();

    float accA = 0.f;
    if (tid < MASK_W) {
        u64 m = ms[tid] & md[tid];
        while (m) {
            const int b = __builtin_ctzll(m);
            accA += t[tid * 64 + b];
            m &= m - 1;
        }
    }
    const float r = P[(size_t)src * Hh + tid] + Q[(size_t)dst * Hh + tid];
    float accB = (r > 0.f) ? r * w2[tid] : 0.f;

    for (int off = 32; off > 0; off >>= 1) {
        accA += __shfl_down(accA, off);
        accB += __shfl_down(accB, off);
    }
    __shared__ float wA[4], wB[4];
    const int wave = tid >> 6;
    if ((tid & 63) == 0) { wA[wave] = accA; wB[wave] = accB; }
    __syncthreads();
    if (tid == 0) {
        const float sA = wA[0] + wA[1] + wA[2] + wA[3];
        const float sB = wB[0] + wB[1] + wB[2] + wB[3];
        const float be = consts[3];
        const float sgn = consts[2];
        const float s = be * sA + sB + consts[1];
        const float m = -sgn * s;
        const float res = fmaxf(m, 0.f) + log1pf(expf(-fabsf(m)));
        out[e] = res;
    }
}

extern "C" void kernel_launch(void* const* d_in, const int* in_sizes, int n_in,
                              void* d_out, int out_size, void* d_ws, size_t ws_size,
                              hipStream_t stream) {
    const float* x     = (const float*)d_in[0];
    const float* adj   = (const float*)d_in[1];
    const int*   tei   = (const int*)d_in[2];
    const float* Wx    = (const float*)d_in[3];
    const float* bx    = (const float*)d_in[4];
    const float* Wc    = (const float*)d_in[5];
    const float* bc    = (const float*)d_in[6];
    const float* Wi    = (const float*)d_in[7];
    const float* bi    = (const float*)d_in[8];
    const float* Wj    = (const float*)d_in[9];
    const float* bj    = (const float*)d_in[10];
    const float* Wf    = (const float*)d_in[11];
    const float* bf_   = (const float*)d_in[12];
    const float* v_    = (const float*)d_in[13];
    const float* bs    = (const float*)d_in[14];
    const float* beta  = (const float*)d_in[15];
    const int*   booln = (const int*)d_in[16];
    float* out = (float*)d_out;

    // workspace layout (fp32 elements)
    float* u      = (float*)d_ws;                // 256
    float* w2     = u + 256;                     // 256
    float* g      = w2 + 256;                    // 256
    float* consts = g + 256;                     // 8 (padded)
    float* t      = consts + 8;                  // 8192
    float* P      = t + 8192;                    // 8192*256 = 8 MB
    float* Q      = P + (size_t)Nn * Hh;         // 8 MB
    u64*   mask   = (u64*)(Q + (size_t)Nn * Hh); // 8192*128 u64 = 8 MB
    // total ~25 MB << ws_size

    pack_kernel<<<(Nn * MASK_W) / 256, 256, 0, stream>>>(adj, mask);
    preA_kernel<<<65, 256, 0, stream>>>(Wc, Wf, v_, bc, bf_, bs, beta, booln,
                                        u, w2, consts);
    preB_kernel<<<65, 256, 0, stream>>>(Wx, bx, u, g, consts);
    pq_kernel<<<Nn / RQ, 256, 0, stream>>>(x, Wi, Wj, bi, bj, g, consts, P, Q, t);
    edge_kernel<<<Ee, 256, 0, stream>>>(mask, tei, P, Q, w2, t, consts, out);
}

// Round 9
// 528.719 us; speedup vs baseline: 1.2457x; 1.0147x over previous
//
#include <hip/hip_runtime.h>
#include <hip/hip_bf16.h>

#define Nn 8192
#define Ee 8192
#define Hh 256
#define MASK_W 128   // 8192 bits / 64

typedef unsigned long long u64;

// ---------------------------------------------------------------------------
// Kernel 1a: preA — parallel precompute stage 1. (identical to R8)
// blocks 0..63 : u[k] = Wc[k,:].v ; w2[k] = Wf[k,:].v   (k = blk*4 + wave)
// block  64    : consts[1] = beta*(bc.v) + bf.v + bs ; consts[2]=sign ; consts[3]=beta
// ---------------------------------------------------------------------------
__global__ void __launch_bounds__(256)
preA_kernel(const float* __restrict__ Wc, const float* __restrict__ Wf,
            const float* __restrict__ v_, const float* __restrict__ bc,
            const float* __restrict__ bf_, const float* __restrict__ bs,
            const float* __restrict__ beta, const int* __restrict__ boolen,
            float* __restrict__ u, float* __restrict__ w2,
            float* __restrict__ consts) {
    const int tid = threadIdx.x;
    if (blockIdx.x < 64) {
        const int wave = tid >> 6;
        const int lane = tid & 63;
        const int k = blockIdx.x * 4 + wave;
        float a = 0.f, b = 0.f;
#pragma unroll
        for (int i = 0; i < 4; ++i) {
            const int j = lane + 64 * i;
            const float vv = v_[j];
            a = fmaf(Wc[k * Hh + j], vv, a);
            b = fmaf(Wf[k * Hh + j], vv, b);
        }
        for (int off = 32; off > 0; off >>= 1) {
            a += __shfl_down(a, off);
            b += __shfl_down(b, off);
        }
        if (lane == 0) { u[k] = a; w2[k] = b; }
        return;
    }
    __shared__ float red[Hh];
    __shared__ float red2[Hh];
    const float vv = v_[tid];
    red[tid]  = bc[tid]  * vv;
    red2[tid] = bf_[tid] * vv;
    __syncthreads();
    for (int s = 128; s > 0; s >>= 1) {
        if (tid < s) { red[tid] += red[tid + s]; red2[tid] += red2[tid + s]; }
        __syncthreads();
    }
    if (tid == 0) {
        const float be = beta[0];
        consts[1] = be * red[0] + red2[0] + bs[0];
        consts[2] = (boolen[0] != 0) ? 1.f : -1.f;
        consts[3] = be;
    }
}

// ---------------------------------------------------------------------------
// Kernel 1b: preB — parallel precompute stage 2. (identical to R8)
// blocks 0..63 : g[k] = u[k] + Wx[k,:].u ; block 64: consts[0] = bx.u
// ---------------------------------------------------------------------------
__global__ void __launch_bounds__(256)
preB_kernel(const float* __restrict__ Wx, const float* __restrict__ bx,
            const float* __restrict__ u, float* __restrict__ g,
            float* __restrict__ consts) {
    const int tid = threadIdx.x;
    if (blockIdx.x < 64) {
        const int wave = tid >> 6;
        const int lane = tid & 63;
        const int k = blockIdx.x * 4 + wave;
        float a = 0.f;
#pragma unroll
        for (int i = 0; i < 4; ++i) {
            const int j = lane + 64 * i;
            a = fmaf(Wx[k * Hh + j], u[j], a);
        }
        for (int off = 32; off > 0; off >>= 1) a += __shfl_down(a, off);
        if (lane == 0) g[k] = u[k] + a;
        return;
    }
    __shared__ float red[Hh];
    red[tid] = bx[tid] * u[tid];
    __syncthreads();
    for (int s = 128; s > 0; s >>= 1) { if (tid < s) red[tid] += red[tid + s]; __syncthreads(); }
    if (tid == 0) consts[0] = red[0];
}

// ---------------------------------------------------------------------------
// Kernel 2: coalesced bit-pack via in-register transpose.
// One wave per half-row (4096 floats -> 64 u64 words). Lane reads contiguous
// float4 (wave = 1KB/instr fully coalesced), nibble per lane, shfl_xor tree
// (1,2,4,8) assembles u64 words on lanes ==0 mod 16, routing shfl + cndmask
// parks word l in lane l. Single coalesced 512B store per wave.
// ---------------------------------------------------------------------------
__global__ void __launch_bounds__(256)
pack_kernel(const float* __restrict__ adj, u64* __restrict__ mask) {
    const int wave_id = blockIdx.x * 4 + (threadIdx.x >> 6);  // 0..16383
    const int lane = threadIdx.x & 63;
    const int row  = wave_id >> 1;
    const int half = wave_id & 1;
    const float4* src = reinterpret_cast<const float4*>(
        adj + (size_t)row * Nn + half * 4096);

    u64 myword = 0;
#pragma unroll
    for (int i = 0; i < 16; ++i) {
        const float4 v = src[i * 64 + lane];
        unsigned int nib = 0;
        nib |= (v.x != 0.f) ? 1u : 0u;
        nib |= (v.y != 0.f) ? 2u : 0u;
        nib |= (v.z != 0.f) ? 4u : 0u;
        nib |= (v.w != 0.f) ? 8u : 0u;
        // byte at lanes ==0 mod 2 (bits 0-3 mine, 4-7 from lane+1)
        const unsigned int t1 = __shfl_xor(nib, 1);
        const unsigned int by = nib | (t1 << 4);
        // u16 at lanes ==0 mod 4
        const unsigned int t2 = __shfl_xor(by, 2);
        const unsigned int h16 = by | (t2 << 8);
        // u32 at lanes ==0 mod 8
        const unsigned int t4 = __shfl_xor(h16, 4);
        const unsigned int w32 = h16 | (t4 << 16);
        // u64 at lanes ==0 mod 16 (lane 16k holds word k of this 256-float chunk)
        const unsigned int t8 = __shfl_xor(w32, 8);
        const u64 w64 = (u64)w32 | ((u64)t8 << 32);
        // route word i*4+k (at src lane 16k) to dst lane i*4+k
        const u64 got = __shfl(w64, (lane & 3) << 4);
        if ((lane >> 2) == i) myword = got;
    }
    mask[(size_t)row * MASK_W + half * 64 + lane] = myword;
}

// ---------------------------------------------------------------------------
// Kernel 3: P = x@Wi + bi, Q = x@Wj + bj (fp32), plus t[n] = x[n].g + c0.
// (identical to R4/R7/R8 measured-good kernel)
// ---------------------------------------------------------------------------
#define RQ 16
__global__ void __launch_bounds__(256)
pq_kernel(const float* __restrict__ x,
          const float* __restrict__ Wi, const float* __restrict__ Wj,
          const float* __restrict__ bi, const float* __restrict__ bj,
          const float* __restrict__ g, const float* __restrict__ consts,
          float* __restrict__ P, float* __restrict__ Q, float* __restrict__ t) {
    __shared__ float xs[RQ][Hh];                 // 16 KB
    const int tid = threadIdx.x;
    const int base = blockIdx.x * RQ;

    {
        const float4* xv = reinterpret_cast<const float4*>(x + (size_t)base * Hh);
        float4* xd = reinterpret_cast<float4*>(&xs[0][0]);
#pragma unroll
        for (int i = tid; i < 1024; i += 256) xd[i] = xv[i];
    }
    __syncthreads();

    {
        const int wave = tid >> 6;
        const int lane = tid & 63;
        const float c0 = consts[0];
#pragma unroll
        for (int r0 = 0; r0 < 4; ++r0) {
            const int r = wave * 4 + r0;
            float s = 0.f;
#pragma unroll
            for (int i = 0; i < 4; ++i) {
                const int c = lane * 4 + i;
                s = fmaf(xs[r][c], g[c], s);
            }
            for (int off = 32; off > 0; off >>= 1) s += __shfl_down(s, off);
            if (lane == 0) t[base + r] = s + c0;
        }
    }

    float accP[RQ], accQ[RQ];
    const float fbi = bi[tid], fbj = bj[tid];
#pragma unroll
    for (int r = 0; r < RQ; ++r) { accP[r] = fbi; accQ[r] = fbj; }

#pragma unroll 4
    for (int k = 0; k < Hh; ++k) {
        const float wiv = Wi[k * Hh + tid];
        const float wjv = Wj[k * Hh + tid];
#pragma unroll
        for (int r = 0; r < RQ; ++r) {
            accP[r] = fmaf(xs[r][k], wiv, accP[r]);
            accQ[r] = fmaf(xs[r][k], wjv, accQ[r]);
        }
    }
#pragma unroll
    for (int r = 0; r < RQ; ++r) {
        P[(size_t)(base + r) * Hh + tid] = accP[r];
        Q[(size_t)(base + r) * Hh + tid] = accQ[r];
    }
}

// ---------------------------------------------------------------------------
// Kernel 4: per-edge block (identical to R4/R7/R8 measured-good kernel).
// ---------------------------------------------------------------------------
__global__ void edge_kernel(const u64* __restrict__ mask, const int* __restrict__ tei,
                            const float* __restrict__ P, const float* __restrict__ Q,
                            const float* __restrict__ w2, const float* __restrict__ t,
                            const float* __restrict__ consts, float* __restrict__ out) {
    const int e = blockIdx.x;
    const int tid = threadIdx.x;
    const int src = tei[e];
    const int dst = tei[Ee + e];

    __shared__ u64 ms[MASK_W];
    __shared__ u64 md[MASK_W];
    if (tid < MASK_W) ms[tid] = mask[(size_t)src * MASK_W + tid];
    else              md[tid - MASK_W] = mask[(size_t)dst * MASK_W + (tid - MASK_W)];
    __syncthreads();

    float accA = 0.f;
    if (tid < MASK_W) {
        u64 m = ms[tid] & md[tid];
        while (m) {
            const int b = __builtin_ctzll(m);
            accA += t[tid * 64 + b];
            m &= m - 1;
        }
    }
    const float r = P[(size_t)src * Hh + tid] + Q[(size_t)dst * Hh + tid];
    float accB = (r > 0.f) ? r * w2[tid] : 0.f;

    for (int off = 32; off > 0; off >>= 1) {
        accA += __shfl_down(accA, off);
        accB += __shfl_down(accB, off);
    }
    __shared__ float wA[4], wB[4];
    const int wave = tid >> 6;
    if ((tid & 63) == 0) { wA[wave] = accA; wB[wave] = accB; }
    __syncthreads();
    if (tid == 0) {
        const float sA = wA[0] + wA[1] + wA[2] + wA[3];
        const float sB = wB[0] + wB[1] + wB[2] + wB[3];
        const float be = consts[3];
        const float sgn = consts[2];
        const float s = be * sA + sB + consts[1];
        const float m = -sgn * s;
        const float res = fmaxf(m, 0.f) + log1pf(expf(-fabsf(m)));
        out[e] = res;
    }
}

extern "C" void kernel_launch(void* const* d_in, const int* in_sizes, int n_in,
                              void* d_out, int out_size, void* d_ws, size_t ws_size,
                              hipStream_t stream) {
    const float* x     = (const float*)d_in[0];
    const float* adj   = (const float*)d_in[1];
    const int*   tei   = (const int*)d_in[2];
    const float* Wx    = (const float*)d_in[3];
    const float* bx    = (const float*)d_in[4];
    const float* Wc    = (const float*)d_in[5];
    const float* bc    = (const float*)d_in[6];
    const float* Wi    = (const float*)d_in[7];
    const float* bi    = (const float*)d_in[8];
    const float* Wj    = (const float*)d_in[9];
    const float* bj    = (const float*)d_in[10];
    const float* Wf    = (const float*)d_in[11];
    const float* bf_   = (const float*)d_in[12];
    const float* v_    = (const float*)d_in[13];
    const float* bs    = (const float*)d_in[14];
    const float* beta  = (const float*)d_in[15];
    const int*   booln = (const int*)d_in[16];
    float* out = (float*)d_out;

    // workspace layout (fp32 elements)
    float* u      = (float*)d_ws;                // 256
    float* w2     = u + 256;                     // 256
    float* g      = w2 + 256;                    // 256
    float* consts = g + 256;                     // 8 (padded)
    float* t      = consts + 8;                  // 8192
    float* P      = t + 8192;                    // 8192*256 = 8 MB
    float* Q      = P + (size_t)Nn * Hh;         // 8 MB
    u64*   mask   = (u64*)(Q + (size_t)Nn * Hh); // 8192*128 u64 = 8 MB
    // total ~25 MB << ws_size

    pack_kernel<<<(Nn * 2) / 4, 256, 0, stream>>>(adj, mask);
    preA_kernel<<<65, 256, 0, stream>>>(Wc, Wf, v_, bc, bf_, bs, beta, booln,
                                        u, w2, consts);
    preB_kernel<<<65, 256, 0, stream>>>(Wx, bx, u, g, consts);
    pq_kernel<<<Nn / RQ, 256, 0, stream>>>(x, Wi, Wj, bi, bj, g, consts, P, Q, t);
    edge_kernel<<<Ee, 256, 0, stream>>>(mask, tei, P, Q, w2, t, consts, out);
}